// Round 14
// baseline (156.959 us; speedup 1.0000x reference)
//
#include <hip/hip_runtime.h>

typedef unsigned short ushort_t;
typedef unsigned int   uint_t;
typedef float    float4v __attribute__((ext_vector_type(4)));
typedef _Float16 h16x8   __attribute__((ext_vector_type(8)));

#define Bsz 32
#define Tsz 1024
#define Din 512
#define Hsz 512
#define Mtot (Bsz * Tsz)                 // 32768
#define ELEMS ((size_t)Mtot * Hsz)       // 16777216

#define GLL16(gp, lp) __builtin_amdgcn_global_load_lds(                        \
    (const __attribute__((address_space(1))) unsigned int*)(gp),               \
    (__attribute__((address_space(3))) unsigned int*)(lp), 16, 0, 0)

#define GLL4(gp, lp) __builtin_amdgcn_global_load_lds(                         \
    (const __attribute__((address_space(1))) unsigned int*)(gp),               \
    (__attribute__((address_space(3))) unsigned int*)(lp), 4, 0, 0)

// ===========================================================================
// Pass 1: exact 2-limb fp16 truncation split with power-of-2 pre-scaling.
// ===========================================================================
__global__ __launch_bounds__(256) void split_fp16x2(
    const float* __restrict__ A, const float* __restrict__ W,
    _Float16* __restrict__ Ah, _Float16* __restrict__ Bh)
{
    const int bid = blockIdx.x, tid = threadIdx.x;
    if (bid < 4096) {
        const size_t e   = ((size_t)bid * 256 + tid) * 16;
        const int    row = (int)(e >> 9);
        const int    col = (int)(e & 511);
        const float4* Af = (const float4*)(A + e);
        h16x8 v0a, v1a, v0b, v1b;
#pragma unroll
        for (int q = 0; q < 4; ++q) {
            float4 x = Af[q];
            const float c[4] = {x.x, x.y, x.z, x.w};
#pragma unroll
            for (int j = 0; j < 4; ++j) {
                const float xs = c[j] * 256.0f;
                const _Float16 h0 = (_Float16)xs;
                const float rf = xs - (float)h0;
                const _Float16 h1 = (_Float16)rf;
                const int idx = q * 4 + j;
                if (idx < 8) { v0a[idx] = h0; v1a[idx] = h1; }
                else         { v0b[idx - 8] = h0; v1b[idx - 8] = h1; }
            }
        }
        _Float16* d0 = Ah + (size_t)row * 1024 + col;
        *(h16x8*)(d0)           = v0a;
        *(h16x8*)(d0 + 8)       = v0b;
        *(h16x8*)(d0 + 512)     = v1a;
        *(h16x8*)(d0 + 512 + 8) = v1b;
    } else {
        const int f4 = (bid - 4096) * 256 + tid;
        const int k  = f4 >> 7;
        const int n4 = (f4 & 127) << 2;
        float4 x = *(const float4*)(W + (size_t)k * Hsz + n4);
        const float c[4] = {x.x, x.y, x.z, x.w};
#pragma unroll
        for (int j = 0; j < 4; ++j) {
            const float ws = c[j] * 2048.0f;
            const _Float16 h0 = (_Float16)ws;
            const float rf = ws - (float)h0;
            const _Float16 h1 = (_Float16)rf;
            _Float16* d = Bh + (size_t)(n4 + j) * 1024 + k;
            d[0]   = h0;
            d[512] = h1;
        }
    }
}

// ===========================================================================
// Pass 2: fp16 2-limb 3-product MFMA GEMM (A0B0 + A0B1 + A1B0) * 2^-19.
// (byte-identical to R9-R13 — verified passing)
// ===========================================================================
#define SA_STAGE(LIMB, KK, SLOTBASE) do {                                      \
    const char* g_ = Ag + (size_t)((LIMB) * 1024) + (size_t)((KK) * 64);       \
    _Pragma("unroll") for (int H = 0; H < 4; ++H)                              \
        GLL16(g_ + (size_t)H * 131072, ldsA + (SLOTBASE) + H * 4096 + lsd);    \
} while (0)

#define SB_STAGE(LIMB, KK, SLOT) do {                                          \
    const char* g_ = Bg + (size_t)((LIMB) * 1024) + (size_t)((KK) * 64);       \
    _Pragma("unroll") for (int H = 0; H < 2; ++H)                              \
        GLL16(g_ + (size_t)H * 131072, ldsB + (SLOT) * 8192 + H * 4096 + lsd); \
} while (0)

#define LD_AF(SLOTBASE) do {                                                   \
    _Pragma("unroll") for (int mf = 0; mf < 8; ++mf)                           \
        af[mf] = *(const h16x8*)(ldsA + (SLOTBASE) + (wm + mf * 16 + lr) * 64  \
                                 + physf * 16);                                \
} while (0)

#define LD_BF(DST, SLOT) do {                                                  \
    _Pragma("unroll") for (int nf = 0; nf < 4; ++nf)                           \
        DST[nf] = *(const h16x8*)(ldsB + (SLOT) * 8192 + (wn + nf * 16 + lr)   \
                                  * 64 + physf * 16);                          \
} while (0)

#define MFMAH(BF) do { __builtin_amdgcn_s_setprio(1);                          \
    _Pragma("unroll") for (int mf = 0; mf < 8; ++mf)                           \
    _Pragma("unroll") for (int nf = 0; nf < 4; ++nf)                           \
        acc[mf][nf] = __builtin_amdgcn_mfma_f32_16x16x32_f16(                  \
            af[mf], BF[nf], acc[mf][nf], 0, 0, 0);                             \
    __builtin_amdgcn_s_setprio(0); } while (0)

#define GATE(N) do { asm volatile("s_waitcnt vmcnt(" #N ")" ::: "memory");     \
    __builtin_amdgcn_sched_barrier(0); __builtin_amdgcn_s_barrier();           \
    asm volatile("" ::: "memory"); } while (0)

__global__ __launch_bounds__(256, 2) void gemm_f16k3(
    const _Float16* __restrict__ Ah, const _Float16* __restrict__ Bh,
    const float* __restrict__ bias, float* __restrict__ C)
{
    __shared__ __align__(16) char lds[65536];
    char* ldsA = lds;
    char* ldsB = lds + 32768;

    const int tid = threadIdx.x;
    const int bid = blockIdx.x;
    const int lin = ((bid & 7) << 6) | (bid >> 3);
    const int m0  = (lin >> 2) << 8;
    const int n0  = (lin & 3) << 7;
    const int w = tid >> 6, lane = tid & 63;
    const int wm = (w & 1) << 7;
    const int wn = (w >> 1) << 6;
    const int lr = lane & 15, lg = lane >> 4;

    const int physf = lg ^ (lr & 3) ^ ((lr >> 2) & 3);

    const int srow = tid >> 2;
    const int schk = tid & 3;
    const int logchk = schk ^ (srow & 3) ^ ((srow >> 2) & 3);
    const int lsd = tid * 16;
    const char* Ag = (const char*)Ah + (size_t)(m0 + srow) * 2048 + logchk * 16;
    const char* Bg = (const char*)Bh + (size_t)(n0 + srow) * 2048 + logchk * 16;

    float4v acc[8][4];
#pragma unroll
    for (int i = 0; i < 8; ++i)
#pragma unroll
        for (int j = 0; j < 4; ++j) acc[i][j] = (float4v)0.f;

    h16x8 af[8], bf0[4], bf1[4];

    SA_STAGE(0, 0, 0);
    SB_STAGE(0, 0, 0); SB_STAGE(1, 0, 1);
    SB_STAGE(0, 1, 2); SB_STAGE(1, 1, 3);
    GATE(0);

#pragma unroll 1
    for (int k = 0; k < 15; ++k) {
        const int s0 = (2 * k) & 3, s1 = (2 * k + 1) & 3;
        GATE(4);
        LD_AF(0); LD_BF(bf0, s0);
        SA_STAGE(1, k, 16384);
        MFMAH(bf0);
        GATE(4);
        LD_BF(bf1, s1);
        SA_STAGE(0, k + 1, 0);
        MFMAH(bf1);
        GATE(4);
        LD_AF(16384);
        if (k < 14) { SB_STAGE(0, k + 2, s0); SB_STAGE(1, k + 2, s1); }
        MFMAH(bf0);
    }
    {
        GATE(0);
        LD_AF(0); LD_BF(bf0, 2);
        SA_STAGE(1, 15, 16384);
        MFMAH(bf0);
        GATE(4);
        LD_BF(bf1, 3);
        MFMAH(bf1);
        GATE(0);
        LD_AF(16384);
        MFMAH(bf0);
    }

    constexpr float INVS = 1.0f / 524288.0f;
#pragma unroll
    for (int nf = 0; nf < 4; ++nf) {
        const int col = n0 + wn + nf * 16 + lr;
        const float bv = bias[col];
#pragma unroll
        for (int mf = 0; mf < 8; ++mf)
#pragma unroll
            for (int j = 0; j < 4; ++j) {
                const int row = m0 + wm + mf * 16 + lg * 4 + j;
                C[(size_t)row * Hsz + col] = fmaf(acc[mf][nf][j], INVS, bv);
            }
    }
}

// ===========================================================================
// Fallback fp32 GEMM (only if d_ws too small)
// ===========================================================================
#define BM 128
#define BN 128
#define BK 16
#define LDSA (BM + 4)
#define LDSB (BN + 4)
__global__ __launch_bounds__(256) void sgemm_currents(
    const float* __restrict__ A, const float* __restrict__ B,
    const float* __restrict__ bias, float* __restrict__ C)
{
    __shared__ float As[BK][LDSA];
    __shared__ float Bs[BK][LDSB];
    const int tid = threadIdx.x;
    const int tx = tid & 15, ty = tid >> 4;
    const int m0 = blockIdx.y * BM, n0 = blockIdx.x * BN;
    const int arow = tid >> 2, ac4 = (tid & 3) * 4;
    const int brow = tid >> 5, bc4 = (tid & 31) * 4;
    float acc[8][8];
#pragma unroll
    for (int i = 0; i < 8; ++i)
#pragma unroll
        for (int j = 0; j < 8; ++j) acc[i][j] = 0.f;
    const float* Abase = A + (size_t)(m0 + arow) * Din + ac4;
    const float* Bbase = B + (size_t)brow * Hsz + n0 + bc4;
    float4 a0 = *(const float4*)Abase;
    float4 a1 = *(const float4*)(Abase + (size_t)64 * Din);
    float4 b0 = *(const float4*)Bbase;
    float4 b1 = *(const float4*)(Bbase + (size_t)8 * Hsz);
    const int NKT = Din / BK;
    for (int kt = 0; kt < NKT; ++kt) {
        const float* apf = (const float*)&a0;
        const float* aqf = (const float*)&a1;
#pragma unroll
        for (int j = 0; j < 4; ++j) As[ac4 + j][arow] = apf[j];
#pragma unroll
        for (int j = 0; j < 4; ++j) As[ac4 + j][arow + 64] = aqf[j];
        *(float4*)&Bs[brow][bc4] = b0;
        *(float4*)&Bs[brow + 8][bc4] = b1;
        __syncthreads();
        if (kt + 1 < NKT) {
            const float* An = Abase + (kt + 1) * BK;
            const float* Bn = Bbase + (size_t)(kt + 1) * BK * Hsz;
            a0 = *(const float4*)An;
            a1 = *(const float4*)(An + (size_t)64 * Din);
            b0 = *(const float4*)Bn;
            b1 = *(const float4*)(Bn + (size_t)8 * Hsz);
        }
#pragma unroll
        for (int k = 0; k < BK; ++k) {
            float4 af0 = *(const float4*)&As[k][ty * 8];
            float4 af1 = *(const float4*)&As[k][ty * 8 + 4];
            float4 bf0 = *(const float4*)&Bs[k][tx * 8];
            float4 bf1 = *(const float4*)&Bs[k][tx * 8 + 4];
            const float av[8] = {af0.x, af0.y, af0.z, af0.w, af1.x, af1.y, af1.z, af1.w};
            const float bv[8] = {bf0.x, bf0.y, bf0.z, bf0.w, bf1.x, bf1.y, bf1.z, bf1.w};
#pragma unroll
            for (int i = 0; i < 8; ++i)
#pragma unroll
                for (int j = 0; j < 8; ++j) acc[i][j] = fmaf(av[i], bv[j], acc[i][j]);
        }
        __syncthreads();
    }
    const float4 bi0 = *(const float4*)&bias[n0 + tx * 8];
    const float4 bi1 = *(const float4*)&bias[n0 + tx * 8 + 4];
#pragma unroll
    for (int i = 0; i < 8; ++i) {
        const size_t row = (size_t)(m0 + ty * 8 + i);
        float4 o0 = make_float4(acc[i][0] + bi0.x, acc[i][1] + bi0.y,
                                acc[i][2] + bi0.z, acc[i][3] + bi0.w);
        float4 o1 = make_float4(acc[i][4] + bi1.x, acc[i][5] + bi1.y,
                                acc[i][6] + bi1.z, acc[i][7] + bi1.w);
        float* cp = C + row * Hsz + n0 + tx * 8;
        *(float4*)cp = o0;
        *(float4*)(cp + 4) = o1;
    }
}

// ===========================================================================
// Pass 3a: recursion-only LIF scan (non-aliased). 256 blocks x 64 thr.
// R13 post-mortem: 1 wave/CU -> single-SIMD issue throughput is the wall;
// the ~14-op surrogate (2 transcendentals) was on the issue path. v5 evicts
// it: per step only {ds_read, fma, fma, store v_pre, select-reset} (~6
// instr). v_pre -> spikes slot; surr_rate recomputes everything pointwise
// at full occupancy. LDS ring + per-chunk vmcnt(0) drain unchanged (proven
// R13, no crash).
// ===========================================================================
__global__ __launch_bounds__(64) void lif_scan_g(
    const float* __restrict__ cur, float* __restrict__ vpre_out,
    float* __restrict__ vfinal)
{
    __shared__ __align__(16) float lbuf[2][32][64];   // 16 KB

    constexpr float A_M  = 0.95122942450071400910f;
    constexpr float OM_M = 1.0f - A_M;
    constexpr float A_S  = 0.81873075307798182354f;

    const int tid   = threadIdx.x;
    const int bid   = blockIdx.x;
    const int batch = bid >> 3;
    const int hbase = (bid & 7) << 6;
    const size_t sbase = (size_t)batch * (size_t)(Tsz * Hsz) + hbase + tid;

    const float* gsrc = cur + sbase;
    float* gpre = vpre_out + sbase;

#pragma unroll
    for (int r = 0; r < 32; ++r)
        GLL4(gsrc + r * 512, &lbuf[0][r][0]);
    asm volatile("s_waitcnt vmcnt(0)" ::: "memory");
    __builtin_amdgcn_sched_barrier(0);

    float v = 0.f, isyn = 0.f;
    int pb = 0;
#pragma unroll 1
    for (int c = 0; c < 32; ++c) {
        if (c < 31) {
            const float* gs = gsrc + (size_t)(c + 1) * 16384;
            float (*db)[64] = lbuf[pb ^ 1];
#pragma unroll
            for (int r = 0; r < 32; ++r)
                GLL4(gs + r * 512, &db[r][0]);
        }
        const float* lrow = &lbuf[pb][0][tid];
        float* pp = gpre + (size_t)c * 16384;
#pragma unroll
        for (int r = 0; r < 32; ++r) {
            isyn = fmaf(A_S, isyn, lrow[r * 64]);
            v    = fmaf(A_M, v, OM_M * isyn);
            pp[r * 512] = v;                          // v_pre (pre-reset)
            v = (v >= 1.0f) ? 0.0f : v;               // reset for the carry
        }
        asm volatile("s_waitcnt vmcnt(0)" ::: "memory");
        __builtin_amdgcn_sched_barrier(0);
        pb ^= 1;
    }

    vfinal[bid * 64 + tid] = v;                       // post-reset final v
}

// ===========================================================================
// Pass 3b: pointwise surrogate/spike/reset + rate partials. 2048 blocks x
// 256 thr = full occupancy on every SIMD. Reads v_pre from the spikes slot,
// overwrites spikes with so, writes vmem = post-reset v. Memory-bound.
// ===========================================================================
__global__ __launch_bounds__(256) void surr_rate(
    float* __restrict__ spk, float* __restrict__ vmm,
    float* __restrict__ partials)
{
    const int tid = threadIdx.x, bid = blockIdx.x;
    float4* sp4 = (float4*)spk;
    float4* vm4 = (float4*)vmm;
    const size_t b0 = (size_t)bid * 2048 + tid;       // float4 units
    float lacc = 0.f;
#pragma unroll
    for (int q = 0; q < 8; ++q) {
        const size_t i = b0 + (size_t)q * 256;
        float4 p = sp4[i];
        const float pv[4] = {p.x, p.y, p.z, p.w};
        float so[4], vp[4];
#pragma unroll
        for (int j = 0; j < 4; ++j) {
            const bool sb = (pv[j] >= 1.0f);
            float x = fminf(fmaf(4.0f, pv[j], -4.0f), 30.0f);
            const float ep = __expf(x);
            const float tt = 1.0f + ep;
            const float rr = __builtin_amdgcn_rcpf(tt * tt);
            const float s2 = sb ? 2.0f : 0.0f;
            so[j] = fmaf(-4.0f * ep, rr, s2);
            vp[j] = sb ? 0.0f : pv[j];
            lacc += so[j];
        }
        sp4[i] = make_float4(so[0], so[1], so[2], so[3]);
        vm4[i] = make_float4(vp[0], vp[1], vp[2], vp[3]);
    }
#pragma unroll
    for (int o = 32; o; o >>= 1) lacc += __shfl_down(lacc, o);
    __shared__ float wsum[4];
    if ((tid & 63) == 0) wsum[tid >> 6] = lacc;
    __syncthreads();
    if (tid == 0) partials[bid] = (wsum[0] + wsum[1]) + (wsum[2] + wsum[3]);
}

__global__ __launch_bounds__(256) void rate_finalize2(
    const float* __restrict__ partials, float* __restrict__ rate)
{
    const int tid = threadIdx.x;
    float s = 0.f;
#pragma unroll
    for (int q = 0; q < 8; ++q) s += partials[q * 256 + tid];
#pragma unroll
    for (int o = 32; o; o >>= 1) s += __shfl_down(s, o);
    __shared__ float wsum[4];
    if ((tid & 63) == 0) wsum[tid >> 6] = s;
    __syncthreads();
    if (tid == 0)
        rate[0] = ((wsum[0] + wsum[1]) + (wsum[2] + wsum[3])) * (1.0f / 16777216.0f);
}

// ===========================================================================
// Fallback fused scan (path 2) + its finalize
// ===========================================================================
__device__ __forceinline__ void lif_step(float c, float& v, float& isyn,
                                         float& so_out)
{
    constexpr float A_M  = 0.95122942450071400910f;
    constexpr float OM_M = 1.0f - A_M;
    constexpr float A_S  = 0.81873075307798182354f;
    isyn = fmaf(A_S, isyn, c);
    v    = fmaf(A_M, v, OM_M * isyn);
    const float sp = (v >= 1.0f) ? 1.0f : 0.0f;
    float x = fmaf(4.0f, v, -4.0f);
    x = fminf(x, 30.0f);
    const float ep = __expf(x);
    const float tt = 1.0f + ep;
    const float surr = 4.0f * ep * __builtin_amdgcn_rcpf(tt * tt);
    so_out = fmaf(2.0f, sp, -surr);
    v = (sp > 0.f) ? 0.0f : v;
}

__global__ __launch_bounds__(64) void lif_scan(
    const float* cur, float* spikes, float* vmem, float* vfinal, float* partials)
{
    const int tid = threadIdx.x;
    const int gid = blockIdx.x * 64 + tid;
    const size_t base = ((size_t)(gid >> 9)) * (size_t)Tsz * Hsz + (gid & 511);

    float v = 0.f, isyn = 0.f, acc = 0.f;
    constexpr int P = 8;
    float ring[P];
#pragma unroll
    for (int p = 0; p < P; ++p) ring[p] = cur[base + (size_t)p * Hsz];

    for (int t = 0; t < Tsz; t += P) {
#pragma unroll
        for (int p = 0; p < P; ++p) {
            const float c = ring[p];
            int tn = t + P + p;
            tn = tn < (Tsz - 1) ? tn : (Tsz - 1);
            ring[p] = cur[base + (size_t)tn * Hsz];

            float so;
            lif_step(c, v, isyn, so);
            const size_t idx = base + (size_t)(t + p) * Hsz;
            spikes[idx] = so;
            vmem[idx]   = v;
            acc += so;
        }
    }
    vfinal[gid] = v;
#pragma unroll
    for (int off = 32; off; off >>= 1) acc += __shfl_down(acc, off);
    if (tid == 0) partials[blockIdx.x] = acc;
}

__global__ __launch_bounds__(256) void rate_finalize(
    const float* __restrict__ partials, float* __restrict__ rate)
{
    const int tid = threadIdx.x;
    float s = partials[tid];
#pragma unroll
    for (int off = 32; off; off >>= 1) s += __shfl_down(s, off);
    __shared__ float wsum[4];
    if ((tid & 63) == 0) wsum[tid >> 6] = s;
    __syncthreads();
    if (tid == 0)
        rate[0] = ((wsum[0] + wsum[1]) + (wsum[2] + wsum[3])) * (1.0f / 16777216.0f);
}

// ===========================================================================
extern "C" void kernel_launch(void* const* d_in, const int* in_sizes, int n_in,
                              void* d_out, int out_size, void* d_ws, size_t ws_size,
                              hipStream_t stream)
{
    const float* inputs = (const float*)d_in[0];
    const float* weight = (const float*)d_in[1];
    const float* bias   = (const float*)d_in[2];

    float* out    = (float*)d_out;
    float* spikes = out;
    float* vmem   = out + ELEMS;
    float* vfinal = out + 2 * ELEMS;
    float* rate   = vfinal + (size_t)Bsz * Hsz;

    float* partials = (float*)d_ws;                  // 2048 floats (8 KiB)
    char*  ws       = (char*)d_ws;

    const size_t HDR   = 16384;                      // partials + slack
    const size_t CUR_B = ELEMS * 4;                  // 64 MiB
    const size_t AH_B  = (size_t)Mtot * 1024 * 2;    // 64 MiB
    const size_t BH_B  = (size_t)Hsz * 1024 * 2;     // 1 MiB

    _Float16 *Ah, *Bh;
    float* cur;
    int path;
    if (ws_size >= HDR + CUR_B + AH_B + BH_B) {
        cur = (float*)(ws + HDR);
        Ah  = (_Float16*)(ws + HDR + CUR_B);
        Bh  = Ah + (size_t)Mtot * 1024;
        path = 0;
    } else if (ws_size >= HDR + CUR_B) {
        cur = (float*)(ws + HDR);
        Ah  = (_Float16*)d_out;                      // scan overwrites later
        Bh  = Ah + (size_t)Mtot * 1024;
        path = 1;
    } else {
        cur = vmem;
        Ah = Bh = nullptr;
        path = 2;
    }

    if (path != 2) {
        split_fp16x2<<<dim3(4096 + 256), 256, 0, stream>>>(inputs, weight, Ah, Bh);
        gemm_f16k3<<<dim3(512), 256, 0, stream>>>(Ah, Bh, bias, cur);
        lif_scan_g<<<dim3(256), 64, 0, stream>>>(cur, spikes, vfinal);
        surr_rate<<<dim3(2048), 256, 0, stream>>>(spikes, vmem, partials);
        rate_finalize2<<<dim3(1), 256, 0, stream>>>(partials, rate);
    } else {
        sgemm_currents<<<dim3(4, 256), 256, 0, stream>>>(inputs, weight, bias, cur);
        lif_scan<<<dim3(256), 64, 0, stream>>>(cur, spikes, vmem, vfinal, partials);
        rate_finalize<<<dim3(1), 256, 0, stream>>>(partials, rate);
    }
}

// Round 15
// 149.977 us; speedup vs baseline: 1.0466x; 1.0466x over previous
//
#include <hip/hip_runtime.h>

typedef unsigned short ushort_t;
typedef unsigned int   uint_t;
typedef float    float4v __attribute__((ext_vector_type(4)));
typedef _Float16 h16x8   __attribute__((ext_vector_type(8)));

#define Bsz 32
#define Tsz 1024
#define Din 512
#define Hsz 512
#define Mtot (Bsz * Tsz)                 // 32768
#define ELEMS ((size_t)Mtot * Hsz)       // 16777216

#define GLL16(gp, lp) __builtin_amdgcn_global_load_lds(                        \
    (const __attribute__((address_space(1))) unsigned int*)(gp),               \
    (__attribute__((address_space(3))) unsigned int*)(lp), 16, 0, 0)

#define GLL4(gp, lp) __builtin_amdgcn_global_load_lds(                         \
    (const __attribute__((address_space(1))) unsigned int*)(gp),               \
    (__attribute__((address_space(3))) unsigned int*)(lp), 4, 0, 0)

// ===========================================================================
// Pass 1: exact 2-limb fp16 truncation split with power-of-2 pre-scaling.
// ===========================================================================
__global__ __launch_bounds__(256) void split_fp16x2(
    const float* __restrict__ A, const float* __restrict__ W,
    _Float16* __restrict__ Ah, _Float16* __restrict__ Bh)
{
    const int bid = blockIdx.x, tid = threadIdx.x;
    if (bid < 4096) {
        const size_t e   = ((size_t)bid * 256 + tid) * 16;
        const int    row = (int)(e >> 9);
        const int    col = (int)(e & 511);
        const float4* Af = (const float4*)(A + e);
        h16x8 v0a, v1a, v0b, v1b;
#pragma unroll
        for (int q = 0; q < 4; ++q) {
            float4 x = Af[q];
            const float c[4] = {x.x, x.y, x.z, x.w};
#pragma unroll
            for (int j = 0; j < 4; ++j) {
                const float xs = c[j] * 256.0f;
                const _Float16 h0 = (_Float16)xs;
                const float rf = xs - (float)h0;
                const _Float16 h1 = (_Float16)rf;
                const int idx = q * 4 + j;
                if (idx < 8) { v0a[idx] = h0; v1a[idx] = h1; }
                else         { v0b[idx - 8] = h0; v1b[idx - 8] = h1; }
            }
        }
        _Float16* d0 = Ah + (size_t)row * 1024 + col;
        *(h16x8*)(d0)           = v0a;
        *(h16x8*)(d0 + 8)       = v0b;
        *(h16x8*)(d0 + 512)     = v1a;
        *(h16x8*)(d0 + 512 + 8) = v1b;
    } else {
        const int f4 = (bid - 4096) * 256 + tid;
        const int k  = f4 >> 7;
        const int n4 = (f4 & 127) << 2;
        float4 x = *(const float4*)(W + (size_t)k * Hsz + n4);
        const float c[4] = {x.x, x.y, x.z, x.w};
#pragma unroll
        for (int j = 0; j < 4; ++j) {
            const float ws = c[j] * 2048.0f;
            const _Float16 h0 = (_Float16)ws;
            const float rf = ws - (float)h0;
            const _Float16 h1 = (_Float16)rf;
            _Float16* d = Bh + (size_t)(n4 + j) * 1024 + k;
            d[0]   = h0;
            d[512] = h1;
        }
    }
}

// ===========================================================================
// Pass 2: fp16 2-limb 3-product MFMA GEMM (A0B0 + A0B1 + A1B0) * 2^-19.
// (byte-identical to R9-R14 — verified passing)
// ===========================================================================
#define SA_STAGE(LIMB, KK, SLOTBASE) do {                                      \
    const char* g_ = Ag + (size_t)((LIMB) * 1024) + (size_t)((KK) * 64);       \
    _Pragma("unroll") for (int H = 0; H < 4; ++H)                              \
        GLL16(g_ + (size_t)H * 131072, ldsA + (SLOTBASE) + H * 4096 + lsd);    \
} while (0)

#define SB_STAGE(LIMB, KK, SLOT) do {                                          \
    const char* g_ = Bg + (size_t)((LIMB) * 1024) + (size_t)((KK) * 64);       \
    _Pragma("unroll") for (int H = 0; H < 2; ++H)                              \
        GLL16(g_ + (size_t)H * 131072, ldsB + (SLOT) * 8192 + H * 4096 + lsd); \
} while (0)

#define LD_AF(SLOTBASE) do {                                                   \
    _Pragma("unroll") for (int mf = 0; mf < 8; ++mf)                           \
        af[mf] = *(const h16x8*)(ldsA + (SLOTBASE) + (wm + mf * 16 + lr) * 64  \
                                 + physf * 16);                                \
} while (0)

#define LD_BF(DST, SLOT) do {                                                  \
    _Pragma("unroll") for (int nf = 0; nf < 4; ++nf)                           \
        DST[nf] = *(const h16x8*)(ldsB + (SLOT) * 8192 + (wn + nf * 16 + lr)   \
                                  * 64 + physf * 16);                          \
} while (0)

#define MFMAH(BF) do { __builtin_amdgcn_s_setprio(1);                          \
    _Pragma("unroll") for (int mf = 0; mf < 8; ++mf)                           \
    _Pragma("unroll") for (int nf = 0; nf < 4; ++nf)                           \
        acc[mf][nf] = __builtin_amdgcn_mfma_f32_16x16x32_f16(                  \
            af[mf], BF[nf], acc[mf][nf], 0, 0, 0);                             \
    __builtin_amdgcn_s_setprio(0); } while (0)

#define GATE(N) do { asm volatile("s_waitcnt vmcnt(" #N ")" ::: "memory");     \
    __builtin_amdgcn_sched_barrier(0); __builtin_amdgcn_s_barrier();           \
    asm volatile("" ::: "memory"); } while (0)

__global__ __launch_bounds__(256, 2) void gemm_f16k3(
    const _Float16* __restrict__ Ah, const _Float16* __restrict__ Bh,
    const float* __restrict__ bias, float* __restrict__ C)
{
    __shared__ __align__(16) char lds[65536];
    char* ldsA = lds;
    char* ldsB = lds + 32768;

    const int tid = threadIdx.x;
    const int bid = blockIdx.x;
    const int lin = ((bid & 7) << 6) | (bid >> 3);
    const int m0  = (lin >> 2) << 8;
    const int n0  = (lin & 3) << 7;
    const int w = tid >> 6, lane = tid & 63;
    const int wm = (w & 1) << 7;
    const int wn = (w >> 1) << 6;
    const int lr = lane & 15, lg = lane >> 4;

    const int physf = lg ^ (lr & 3) ^ ((lr >> 2) & 3);

    const int srow = tid >> 2;
    const int schk = tid & 3;
    const int logchk = schk ^ (srow & 3) ^ ((srow >> 2) & 3);
    const int lsd = tid * 16;
    const char* Ag = (const char*)Ah + (size_t)(m0 + srow) * 2048 + logchk * 16;
    const char* Bg = (const char*)Bh + (size_t)(n0 + srow) * 2048 + logchk * 16;

    float4v acc[8][4];
#pragma unroll
    for (int i = 0; i < 8; ++i)
#pragma unroll
        for (int j = 0; j < 4; ++j) acc[i][j] = (float4v)0.f;

    h16x8 af[8], bf0[4], bf1[4];

    SA_STAGE(0, 0, 0);
    SB_STAGE(0, 0, 0); SB_STAGE(1, 0, 1);
    SB_STAGE(0, 1, 2); SB_STAGE(1, 1, 3);
    GATE(0);

#pragma unroll 1
    for (int k = 0; k < 15; ++k) {
        const int s0 = (2 * k) & 3, s1 = (2 * k + 1) & 3;
        GATE(4);
        LD_AF(0); LD_BF(bf0, s0);
        SA_STAGE(1, k, 16384);
        MFMAH(bf0);
        GATE(4);
        LD_BF(bf1, s1);
        SA_STAGE(0, k + 1, 0);
        MFMAH(bf1);
        GATE(4);
        LD_AF(16384);
        if (k < 14) { SB_STAGE(0, k + 2, s0); SB_STAGE(1, k + 2, s1); }
        MFMAH(bf0);
    }
    {
        GATE(0);
        LD_AF(0); LD_BF(bf0, 2);
        SA_STAGE(1, 15, 16384);
        MFMAH(bf0);
        GATE(4);
        LD_BF(bf1, 3);
        MFMAH(bf1);
        GATE(0);
        LD_AF(16384);
        MFMAH(bf0);
    }

    constexpr float INVS = 1.0f / 524288.0f;
#pragma unroll
    for (int nf = 0; nf < 4; ++nf) {
        const int col = n0 + wn + nf * 16 + lr;
        const float bv = bias[col];
#pragma unroll
        for (int mf = 0; mf < 8; ++mf)
#pragma unroll
            for (int j = 0; j < 4; ++j) {
                const int row = m0 + wm + mf * 16 + lg * 4 + j;
                C[(size_t)row * Hsz + col] = fmaf(acc[mf][nf][j], INVS, bv);
            }
    }
}

// ===========================================================================
// Fallback fp32 GEMM (only if d_ws too small)
// ===========================================================================
#define BM 128
#define BN 128
#define BK 16
#define LDSA (BM + 4)
#define LDSB (BN + 4)
__global__ __launch_bounds__(256) void sgemm_currents(
    const float* __restrict__ A, const float* __restrict__ B,
    const float* __restrict__ bias, float* __restrict__ C)
{
    __shared__ float As[BK][LDSA];
    __shared__ float Bs[BK][LDSB];
    const int tid = threadIdx.x;
    const int tx = tid & 15, ty = tid >> 4;
    const int m0 = blockIdx.y * BM, n0 = blockIdx.x * BN;
    const int arow = tid >> 2, ac4 = (tid & 3) * 4;
    const int brow = tid >> 5, bc4 = (tid & 31) * 4;
    float acc[8][8];
#pragma unroll
    for (int i = 0; i < 8; ++i)
#pragma unroll
        for (int j = 0; j < 8; ++j) acc[i][j] = 0.f;
    const float* Abase = A + (size_t)(m0 + arow) * Din + ac4;
    const float* Bbase = B + (size_t)brow * Hsz + n0 + bc4;
    float4 a0 = *(const float4*)Abase;
    float4 a1 = *(const float4*)(Abase + (size_t)64 * Din);
    float4 b0 = *(const float4*)Bbase;
    float4 b1 = *(const float4*)(Bbase + (size_t)8 * Hsz);
    const int NKT = Din / BK;
    for (int kt = 0; kt < NKT; ++kt) {
        const float* apf = (const float*)&a0;
        const float* aqf = (const float*)&a1;
#pragma unroll
        for (int j = 0; j < 4; ++j) As[ac4 + j][arow] = apf[j];
#pragma unroll
        for (int j = 0; j < 4; ++j) As[ac4 + j][arow + 64] = aqf[j];
        *(float4*)&Bs[brow][bc4] = b0;
        *(float4*)&Bs[brow + 8][bc4] = b1;
        __syncthreads();
        if (kt + 1 < NKT) {
            const float* An = Abase + (kt + 1) * BK;
            const float* Bn = Bbase + (size_t)(kt + 1) * BK * Hsz;
            a0 = *(const float4*)An;
            a1 = *(const float4*)(An + (size_t)64 * Din);
            b0 = *(const float4*)Bn;
            b1 = *(const float4*)(Bn + (size_t)8 * Hsz);
        }
#pragma unroll
        for (int k = 0; k < BK; ++k) {
            float4 af0 = *(const float4*)&As[k][ty * 8];
            float4 af1 = *(const float4*)&As[k][ty * 8 + 4];
            float4 bf0 = *(const float4*)&Bs[k][tx * 8];
            float4 bf1 = *(const float4*)&Bs[k][tx * 8 + 4];
            const float av[8] = {af0.x, af0.y, af0.z, af0.w, af1.x, af1.y, af1.z, af1.w};
            const float bv[8] = {bf0.x, bf0.y, bf0.z, bf0.w, bf1.x, bf1.y, bf1.z, bf1.w};
#pragma unroll
            for (int i = 0; i < 8; ++i)
#pragma unroll
                for (int j = 0; j < 8; ++j) acc[i][j] = fmaf(av[i], bv[j], acc[i][j]);
        }
        __syncthreads();
    }
    const float4 bi0 = *(const float4*)&bias[n0 + tx * 8];
    const float4 bi1 = *(const float4*)&bias[n0 + tx * 8 + 4];
#pragma unroll
    for (int i = 0; i < 8; ++i) {
        const size_t row = (size_t)(m0 + ty * 8 + i);
        float4 o0 = make_float4(acc[i][0] + bi0.x, acc[i][1] + bi0.y,
                                acc[i][2] + bi0.z, acc[i][3] + bi0.w);
        float4 o1 = make_float4(acc[i][4] + bi1.x, acc[i][5] + bi1.y,
                                acc[i][6] + bi1.z, acc[i][7] + bi1.w);
        float* cp = C + row * Hsz + n0 + tx * 8;
        *(float4*)cp = o0;
        *(float4*)(cp + 4) = o1;
    }
}

// ===========================================================================
// Pass 3a: fused LIF scan (non-aliased), R13 structure + counted drain.
// Per 32-step chunk: 32 GLL4 prefetch + 64 stores, then GATE vmcnt(63):
// since vmcnt retires IN ORDER (m135), with queue [old stores][32 loads]
// [64 stores] waiting to <=63 outstanding retires all loads + at most one
// early store (issued ~600cyc prior) — the chunk's stores stay in flight,
// removing the ~400cyc store-completion stall that vmcnt(0) exposed per
// chunk. Fused = 192 MiB total traffic (vs 320 MiB for the split scheme).
// ===========================================================================
__global__ __launch_bounds__(64) void lif_scan_g(
    const float* __restrict__ cur, float* __restrict__ spikes,
    float* __restrict__ vmem, float* __restrict__ vfinal,
    float* __restrict__ partials)
{
    __shared__ __align__(16) float lbuf[2][32][64];   // 16 KB

    constexpr float A_M  = 0.95122942450071400910f;
    constexpr float OM_M = 1.0f - A_M;
    constexpr float A_S  = 0.81873075307798182354f;

    const int tid   = threadIdx.x;
    const int bid   = blockIdx.x;
    const int batch = bid >> 3;
    const int hbase = (bid & 7) << 6;
    const size_t sbase = (size_t)batch * (size_t)(Tsz * Hsz) + hbase + tid;

    const float* gsrc = cur + sbase;
    float* gspk = spikes + sbase;
    float* gvmm = vmem + sbase;

#pragma unroll
    for (int r = 0; r < 32; ++r)
        GLL4(gsrc + r * 512, &lbuf[0][r][0]);
    asm volatile("s_waitcnt vmcnt(0)" ::: "memory");
    __builtin_amdgcn_sched_barrier(0);

    float v = 0.f, isyn = 0.f, acc = 0.f;
    int pb = 0;
#pragma unroll 1
    for (int c = 0; c < 32; ++c) {
        if (c < 31) {                                 // prefetch next chunk
            const float* gs = gsrc + (size_t)(c + 1) * 16384;
            float (*db)[64] = lbuf[pb ^ 1];
#pragma unroll
            for (int r = 0; r < 32; ++r)
                GLL4(gs + r * 512, &db[r][0]);
        }
        const float* lrow = &lbuf[pb][0][tid];
        float* sp = gspk + (size_t)c * 16384;
        float* vp = gvmm + (size_t)c * 16384;
#pragma unroll
        for (int r = 0; r < 32; ++r) {
            isyn = fmaf(A_S, isyn, lrow[r * 64]);
            v    = fmaf(A_M, v, OM_M * isyn);
            const bool sb = (v >= 1.0f);
            float x = fminf(fmaf(4.0f, v, -4.0f), 30.0f);
            const float ep = __expf(x);
            const float tt = 1.0f + ep;
            const float rr = __builtin_amdgcn_rcpf(tt * tt);
            const float s2 = sb ? 2.0f : 0.0f;
            const float so = fmaf(-4.0f * ep, rr, s2);
            v = sb ? 0.0f : v;
            acc += so;
            sp[r * 512] = so;
            vp[r * 512] = v;
        }
        // counted drain: loads complete, stores stay in flight
        asm volatile("s_waitcnt vmcnt(63)" ::: "memory");
        __builtin_amdgcn_sched_barrier(0);
        pb ^= 1;
    }

    vfinal[bid * 64 + tid] = v;
#pragma unroll
    for (int o = 32; o; o >>= 1) acc += __shfl_down(acc, o);
    if (tid == 0) partials[blockIdx.x] = acc;
}

// ===========================================================================
// Pass 3b: ALIAS-SAFE fallback scan (cur may be the vmem region).
// ===========================================================================
__device__ __forceinline__ void lif_step(float c, float& v, float& isyn,
                                         float& so_out)
{
    constexpr float A_M  = 0.95122942450071400910f;
    constexpr float OM_M = 1.0f - A_M;
    constexpr float A_S  = 0.81873075307798182354f;
    isyn = fmaf(A_S, isyn, c);
    v    = fmaf(A_M, v, OM_M * isyn);
    const float sp = (v >= 1.0f) ? 1.0f : 0.0f;
    float x = fmaf(4.0f, v, -4.0f);
    x = fminf(x, 30.0f);
    const float ep = __expf(x);
    const float tt = 1.0f + ep;
    const float surr = 4.0f * ep * __builtin_amdgcn_rcpf(tt * tt);
    so_out = fmaf(2.0f, sp, -surr);
    v = (sp > 0.f) ? 0.0f : v;
}

__global__ __launch_bounds__(64) void lif_scan(
    const float* cur, float* spikes, float* vmem, float* vfinal, float* partials)
{
    const int tid = threadIdx.x;
    const int gid = blockIdx.x * 64 + tid;
    const size_t base = ((size_t)(gid >> 9)) * (size_t)Tsz * Hsz + (gid & 511);

    float v = 0.f, isyn = 0.f, acc = 0.f;
    constexpr int P = 8;
    float ring[P];
#pragma unroll
    for (int p = 0; p < P; ++p) ring[p] = cur[base + (size_t)p * Hsz];

    for (int t = 0; t < Tsz; t += P) {
#pragma unroll
        for (int p = 0; p < P; ++p) {
            const float c = ring[p];
            int tn = t + P + p;
            tn = tn < (Tsz - 1) ? tn : (Tsz - 1);
            ring[p] = cur[base + (size_t)tn * Hsz];

            float so;
            lif_step(c, v, isyn, so);
            const size_t idx = base + (size_t)(t + p) * Hsz;
            spikes[idx] = so;
            vmem[idx]   = v;
            acc += so;
        }
    }
    vfinal[gid] = v;
#pragma unroll
    for (int off = 32; off; off >>= 1) acc += __shfl_down(acc, off);
    if (tid == 0) partials[blockIdx.x] = acc;
}

__global__ __launch_bounds__(256) void rate_finalize(
    const float* __restrict__ partials, float* __restrict__ rate)
{
    const int tid = threadIdx.x;
    float s = partials[tid];
#pragma unroll
    for (int off = 32; off; off >>= 1) s += __shfl_down(s, off);
    __shared__ float wsum[4];
    if ((tid & 63) == 0) wsum[tid >> 6] = s;
    __syncthreads();
    if (tid == 0)
        rate[0] = ((wsum[0] + wsum[1]) + (wsum[2] + wsum[3])) * (1.0f / 16777216.0f);
}

// ===========================================================================
extern "C" void kernel_launch(void* const* d_in, const int* in_sizes, int n_in,
                              void* d_out, int out_size, void* d_ws, size_t ws_size,
                              hipStream_t stream)
{
    const float* inputs = (const float*)d_in[0];
    const float* weight = (const float*)d_in[1];
    const float* bias   = (const float*)d_in[2];

    float* out    = (float*)d_out;
    float* spikes = out;
    float* vmem   = out + ELEMS;
    float* vfinal = out + 2 * ELEMS;
    float* rate   = vfinal + (size_t)Bsz * Hsz;

    float* partials = (float*)d_ws;                  // 256 floats
    char*  ws       = (char*)d_ws;

    const size_t HDR   = 16384;
    const size_t CUR_B = ELEMS * 4;                  // 64 MiB
    const size_t AH_B  = (size_t)Mtot * 1024 * 2;    // 64 MiB
    const size_t BH_B  = (size_t)Hsz * 1024 * 2;     // 1 MiB

    _Float16 *Ah, *Bh;
    float* cur;
    int path;
    if (ws_size >= HDR + CUR_B + AH_B + BH_B) {
        cur = (float*)(ws + HDR);
        Ah  = (_Float16*)(ws + HDR + CUR_B);
        Bh  = Ah + (size_t)Mtot * 1024;
        path = 0;
    } else if (ws_size >= HDR + CUR_B) {
        cur = (float*)(ws + HDR);
        Ah  = (_Float16*)d_out;                      // scan overwrites later
        Bh  = Ah + (size_t)Mtot * 1024;
        path = 1;
    } else {
        cur = vmem;
        Ah = Bh = nullptr;
        path = 2;
    }

    if (path != 2) {
        split_fp16x2<<<dim3(4096 + 256), 256, 0, stream>>>(inputs, weight, Ah, Bh);
        gemm_f16k3<<<dim3(512), 256, 0, stream>>>(Ah, Bh, bias, cur);
        lif_scan_g<<<dim3(256), 64, 0, stream>>>(cur, spikes, vmem, vfinal, partials);
    } else {
        sgemm_currents<<<dim3(4, 256), 256, 0, stream>>>(inputs, weight, bias, cur);
        lif_scan<<<dim3(256), 64, 0, stream>>>(cur, spikes, vmem, vfinal, partials);
    }
    rate_finalize<<<dim3(1), 256, 0, stream>>>(partials, rate);
}

// Round 16
// 139.224 us; speedup vs baseline: 1.1274x; 1.0772x over previous
//
#include <hip/hip_runtime.h>

typedef unsigned short ushort_t;
typedef unsigned int   uint_t;
typedef float    float4v __attribute__((ext_vector_type(4)));
typedef _Float16 h16x8   __attribute__((ext_vector_type(8)));

#define Bsz 32
#define Tsz 1024
#define Din 512
#define Hsz 512
#define Mtot (Bsz * Tsz)                 // 32768
#define ELEMS ((size_t)Mtot * Hsz)       // 16777216

#define GLL16(gp, lp) __builtin_amdgcn_global_load_lds(                        \
    (const __attribute__((address_space(1))) unsigned int*)(gp),               \
    (__attribute__((address_space(3))) unsigned int*)(lp), 16, 0, 0)

#define GLL4(gp, lp) __builtin_amdgcn_global_load_lds(                         \
    (const __attribute__((address_space(1))) unsigned int*)(gp),               \
    (__attribute__((address_space(3))) unsigned int*)(lp), 4, 0, 0)

// ===========================================================================
// Pass 1: exact 2-limb fp16 truncation split with power-of-2 pre-scaling.
// ===========================================================================
__global__ __launch_bounds__(256) void split_fp16x2(
    const float* __restrict__ A, const float* __restrict__ W,
    _Float16* __restrict__ Ah, _Float16* __restrict__ Bh)
{
    const int bid = blockIdx.x, tid = threadIdx.x;
    if (bid < 4096) {
        const size_t e   = ((size_t)bid * 256 + tid) * 16;
        const int    row = (int)(e >> 9);
        const int    col = (int)(e & 511);
        const float4* Af = (const float4*)(A + e);
        h16x8 v0a, v1a, v0b, v1b;
#pragma unroll
        for (int q = 0; q < 4; ++q) {
            float4 x = Af[q];
            const float c[4] = {x.x, x.y, x.z, x.w};
#pragma unroll
            for (int j = 0; j < 4; ++j) {
                const float xs = c[j] * 256.0f;
                const _Float16 h0 = (_Float16)xs;
                const float rf = xs - (float)h0;
                const _Float16 h1 = (_Float16)rf;
                const int idx = q * 4 + j;
                if (idx < 8) { v0a[idx] = h0; v1a[idx] = h1; }
                else         { v0b[idx - 8] = h0; v1b[idx - 8] = h1; }
            }
        }
        _Float16* d0 = Ah + (size_t)row * 1024 + col;
        *(h16x8*)(d0)           = v0a;
        *(h16x8*)(d0 + 8)       = v0b;
        *(h16x8*)(d0 + 512)     = v1a;
        *(h16x8*)(d0 + 512 + 8) = v1b;
    } else {
        const int f4 = (bid - 4096) * 256 + tid;
        const int k  = f4 >> 7;
        const int n4 = (f4 & 127) << 2;
        float4 x = *(const float4*)(W + (size_t)k * Hsz + n4);
        const float c[4] = {x.x, x.y, x.z, x.w};
#pragma unroll
        for (int j = 0; j < 4; ++j) {
            const float ws = c[j] * 2048.0f;
            const _Float16 h0 = (_Float16)ws;
            const float rf = ws - (float)h0;
            const _Float16 h1 = (_Float16)rf;
            _Float16* d = Bh + (size_t)(n4 + j) * 1024 + k;
            d[0]   = h0;
            d[512] = h1;
        }
    }
}

// ===========================================================================
// Pass 2: fp16 2-limb 3-product MFMA GEMM (A0B0 + A0B1 + A1B0) * 2^-19.
// (byte-identical to R9-R15 — verified passing)
// ===========================================================================
#define SA_STAGE(LIMB, KK, SLOTBASE) do {                                      \
    const char* g_ = Ag + (size_t)((LIMB) * 1024) + (size_t)((KK) * 64);       \
    _Pragma("unroll") for (int H = 0; H < 4; ++H)                              \
        GLL16(g_ + (size_t)H * 131072, ldsA + (SLOTBASE) + H * 4096 + lsd);    \
} while (0)

#define SB_STAGE(LIMB, KK, SLOT) do {                                          \
    const char* g_ = Bg + (size_t)((LIMB) * 1024) + (size_t)((KK) * 64);       \
    _Pragma("unroll") for (int H = 0; H < 2; ++H)                              \
        GLL16(g_ + (size_t)H * 131072, ldsB + (SLOT) * 8192 + H * 4096 + lsd); \
} while (0)

#define LD_AF(SLOTBASE) do {                                                   \
    _Pragma("unroll") for (int mf = 0; mf < 8; ++mf)                           \
        af[mf] = *(const h16x8*)(ldsA + (SLOTBASE) + (wm + mf * 16 + lr) * 64  \
                                 + physf * 16);                                \
} while (0)

#define LD_BF(DST, SLOT) do {                                                  \
    _Pragma("unroll") for (int nf = 0; nf < 4; ++nf)                           \
        DST[nf] = *(const h16x8*)(ldsB + (SLOT) * 8192 + (wn + nf * 16 + lr)   \
                                  * 64 + physf * 16);                          \
} while (0)

#define MFMAH(BF) do { __builtin_amdgcn_s_setprio(1);                          \
    _Pragma("unroll") for (int mf = 0; mf < 8; ++mf)                           \
    _Pragma("unroll") for (int nf = 0; nf < 4; ++nf)                           \
        acc[mf][nf] = __builtin_amdgcn_mfma_f32_16x16x32_f16(                  \
            af[mf], BF[nf], acc[mf][nf], 0, 0, 0);                             \
    __builtin_amdgcn_s_setprio(0); } while (0)

#define GATE(N) do { asm volatile("s_waitcnt vmcnt(" #N ")" ::: "memory");     \
    __builtin_amdgcn_sched_barrier(0); __builtin_amdgcn_s_barrier();           \
    asm volatile("" ::: "memory"); } while (0)

__global__ __launch_bounds__(256, 2) void gemm_f16k3(
    const _Float16* __restrict__ Ah, const _Float16* __restrict__ Bh,
    const float* __restrict__ bias, float* __restrict__ C)
{
    __shared__ __align__(16) char lds[65536];
    char* ldsA = lds;
    char* ldsB = lds + 32768;

    const int tid = threadIdx.x;
    const int bid = blockIdx.x;
    const int lin = ((bid & 7) << 6) | (bid >> 3);
    const int m0  = (lin >> 2) << 8;
    const int n0  = (lin & 3) << 7;
    const int w = tid >> 6, lane = tid & 63;
    const int wm = (w & 1) << 7;
    const int wn = (w >> 1) << 6;
    const int lr = lane & 15, lg = lane >> 4;

    const int physf = lg ^ (lr & 3) ^ ((lr >> 2) & 3);

    const int srow = tid >> 2;
    const int schk = tid & 3;
    const int logchk = schk ^ (srow & 3) ^ ((srow >> 2) & 3);
    const int lsd = tid * 16;
    const char* Ag = (const char*)Ah + (size_t)(m0 + srow) * 2048 + logchk * 16;
    const char* Bg = (const char*)Bh + (size_t)(n0 + srow) * 2048 + logchk * 16;

    float4v acc[8][4];
#pragma unroll
    for (int i = 0; i < 8; ++i)
#pragma unroll
        for (int j = 0; j < 4; ++j) acc[i][j] = (float4v)0.f;

    h16x8 af[8], bf0[4], bf1[4];

    SA_STAGE(0, 0, 0);
    SB_STAGE(0, 0, 0); SB_STAGE(1, 0, 1);
    SB_STAGE(0, 1, 2); SB_STAGE(1, 1, 3);
    GATE(0);

#pragma unroll 1
    for (int k = 0; k < 15; ++k) {
        const int s0 = (2 * k) & 3, s1 = (2 * k + 1) & 3;
        GATE(4);
        LD_AF(0); LD_BF(bf0, s0);
        SA_STAGE(1, k, 16384);
        MFMAH(bf0);
        GATE(4);
        LD_BF(bf1, s1);
        SA_STAGE(0, k + 1, 0);
        MFMAH(bf1);
        GATE(4);
        LD_AF(16384);
        if (k < 14) { SB_STAGE(0, k + 2, s0); SB_STAGE(1, k + 2, s1); }
        MFMAH(bf0);
    }
    {
        GATE(0);
        LD_AF(0); LD_BF(bf0, 2);
        SA_STAGE(1, 15, 16384);
        MFMAH(bf0);
        GATE(4);
        LD_BF(bf1, 3);
        MFMAH(bf1);
        GATE(0);
        LD_AF(16384);
        MFMAH(bf0);
    }

    constexpr float INVS = 1.0f / 524288.0f;
#pragma unroll
    for (int nf = 0; nf < 4; ++nf) {
        const int col = n0 + wn + nf * 16 + lr;
        const float bv = bias[col];
#pragma unroll
        for (int mf = 0; mf < 8; ++mf)
#pragma unroll
            for (int j = 0; j < 4; ++j) {
                const int row = m0 + wm + mf * 16 + lg * 4 + j;
                C[(size_t)row * Hsz + col] = fmaf(acc[mf][nf][j], INVS, bv);
            }
    }
}

// ===========================================================================
// Fallback fp32 GEMM (only if d_ws too small)
// ===========================================================================
#define BM 128
#define BN 128
#define BK 16
#define LDSA (BM + 4)
#define LDSB (BN + 4)
__global__ __launch_bounds__(256) void sgemm_currents(
    const float* __restrict__ A, const float* __restrict__ B,
    const float* __restrict__ bias, float* __restrict__ C)
{
    __shared__ float As[BK][LDSA];
    __shared__ float Bs[BK][LDSB];
    const int tid = threadIdx.x;
    const int tx = tid & 15, ty = tid >> 4;
    const int m0 = blockIdx.y * BM, n0 = blockIdx.x * BN;
    const int arow = tid >> 2, ac4 = (tid & 3) * 4;
    const int brow = tid >> 5, bc4 = (tid & 31) * 4;
    float acc[8][8];
#pragma unroll
    for (int i = 0; i < 8; ++i)
#pragma unroll
        for (int j = 0; j < 8; ++j) acc[i][j] = 0.f;
    const float* Abase = A + (size_t)(m0 + arow) * Din + ac4;
    const float* Bbase = B + (size_t)brow * Hsz + n0 + bc4;
    float4 a0 = *(const float4*)Abase;
    float4 a1 = *(const float4*)(Abase + (size_t)64 * Din);
    float4 b0 = *(const float4*)Bbase;
    float4 b1 = *(const float4*)(Bbase + (size_t)8 * Hsz);
    const int NKT = Din / BK;
    for (int kt = 0; kt < NKT; ++kt) {
        const float* apf = (const float*)&a0;
        const float* aqf = (const float*)&a1;
#pragma unroll
        for (int j = 0; j < 4; ++j) As[ac4 + j][arow] = apf[j];
#pragma unroll
        for (int j = 0; j < 4; ++j) As[ac4 + j][arow + 64] = aqf[j];
        *(float4*)&Bs[brow][bc4] = b0;
        *(float4*)&Bs[brow + 8][bc4] = b1;
        __syncthreads();
        if (kt + 1 < NKT) {
            const float* An = Abase + (kt + 1) * BK;
            const float* Bn = Bbase + (size_t)(kt + 1) * BK * Hsz;
            a0 = *(const float4*)An;
            a1 = *(const float4*)(An + (size_t)64 * Din);
            b0 = *(const float4*)Bn;
            b1 = *(const float4*)(Bn + (size_t)8 * Hsz);
        }
#pragma unroll
        for (int k = 0; k < BK; ++k) {
            float4 af0 = *(const float4*)&As[k][ty * 8];
            float4 af1 = *(const float4*)&As[k][ty * 8 + 4];
            float4 bf0 = *(const float4*)&Bs[k][tx * 8];
            float4 bf1 = *(const float4*)&Bs[k][tx * 8 + 4];
            const float av[8] = {af0.x, af0.y, af0.z, af0.w, af1.x, af1.y, af1.z, af1.w};
            const float bv[8] = {bf0.x, bf0.y, bf0.z, bf0.w, bf1.x, bf1.y, bf1.z, bf1.w};
#pragma unroll
            for (int i = 0; i < 8; ++i)
#pragma unroll
                for (int j = 0; j < 8; ++j) acc[i][j] = fmaf(av[i], bv[j], acc[i][j]);
        }
        __syncthreads();
    }
    const float4 bi0 = *(const float4*)&bias[n0 + tx * 8];
    const float4 bi1 = *(const float4*)&bias[n0 + tx * 8 + 4];
#pragma unroll
    for (int i = 0; i < 8; ++i) {
        const size_t row = (size_t)(m0 + ty * 8 + i);
        float4 o0 = make_float4(acc[i][0] + bi0.x, acc[i][1] + bi0.y,
                                acc[i][2] + bi0.z, acc[i][3] + bi0.w);
        float4 o1 = make_float4(acc[i][4] + bi1.x, acc[i][5] + bi1.y,
                                acc[i][6] + bi1.z, acc[i][7] + bi1.w);
        float* cp = C + row * Hsz + n0 + tx * 8;
        *(float4*)cp = o0;
        *(float4*)(cp + 4) = o1;
    }
}

// ===========================================================================
// Pass 3a: producer-consumer LIF scan (non-aliased). 256 blocks x 128 thr
// (2 waves on 2 different SIMDs of one CU).
//   Wave 0 (producer): GLL4-prefetch cur chunk, recursion only
//     {ds_read, fma, fma, ds_write v_pre, reset-select} ~18 cyc/step.
//   Wave 1 (consumer): reads v_pre from LDS ring, surrogate + both global
//     stores (~40 cyc/step) — concurrent on its own SIMD.
// Sync: 1 raw s_barrier per 32-step chunk. Producer drains its GLL4s +
// LDS writes (vmcnt0+lgkmcnt0) before each barrier; consumer's stores are
// NEVER drained in-loop. Barrier ledger: both waves execute exactly 33.
// pbuf parity: written phase k, read phase k+1, overwritten phase k+2 —
// barrier-separated. lbuf is producer-private.
// ===========================================================================
__global__ __launch_bounds__(128) void lif_scan_pc(
    const float* __restrict__ cur, float* __restrict__ spikes,
    float* __restrict__ vmem, float* __restrict__ vfinal,
    float* __restrict__ partials)
{
    __shared__ __align__(16) float lbuf[2][32][64];   // cur ring (producer)
    __shared__ __align__(16) float pbuf[2][32][64];   // v_pre ring (P->C)

    constexpr float A_M  = 0.95122942450071400910f;
    constexpr float OM_M = 1.0f - A_M;
    constexpr float A_S  = 0.81873075307798182354f;

    const int tid  = threadIdx.x;
    const int lane = tid & 63;
    const int wv   = tid >> 6;
    const int bid  = blockIdx.x;
    const int batch = bid >> 3;
    const int hbase = (bid & 7) << 6;
    const size_t sbase = (size_t)batch * (size_t)(Tsz * Hsz) + hbase + lane;

    if (wv == 0) {
        // ---------------- producer: recursion ----------------
        const float* gsrc = cur + sbase;
#pragma unroll
        for (int r = 0; r < 32; ++r)
            GLL4(gsrc + r * 512, &lbuf[0][r][0]);
        asm volatile("s_waitcnt vmcnt(0)" ::: "memory");
        __builtin_amdgcn_sched_barrier(0);

        float v = 0.f, isyn = 0.f;
#pragma unroll 1
        for (int c = 0; c < 32; ++c) {
            if (c < 31) {
                const float* gs = gsrc + (size_t)(c + 1) * 16384;
                float (*db)[64] = lbuf[(c + 1) & 1];
#pragma unroll
                for (int r = 0; r < 32; ++r)
                    GLL4(gs + r * 512, &db[r][0]);
            }
            const float* lrow = &lbuf[c & 1][0][lane];
            float* prow = &pbuf[c & 1][0][lane];
#pragma unroll
            for (int r = 0; r < 32; ++r) {
                isyn = fmaf(A_S, isyn, lrow[r * 64]);
                v    = fmaf(A_M, v, OM_M * isyn);
                prow[r * 64] = v;                     // v_pre
                v = (v >= 1.0f) ? 0.0f : v;           // reset carry
            }
            asm volatile("s_waitcnt vmcnt(0) lgkmcnt(0)" ::: "memory");
            __builtin_amdgcn_sched_barrier(0);
            __builtin_amdgcn_s_barrier();             // barrier #c
            asm volatile("" ::: "memory");
        }
        vfinal[bid * 64 + lane] = v;
        __builtin_amdgcn_s_barrier();                 // barrier #32
    } else {
        // ---------------- consumer: surrogate + stores ----------------
        float* gspk = spikes + sbase;
        float* gvmm = vmem + sbase;
        float acc = 0.f;

        __builtin_amdgcn_s_barrier();                 // barrier #0
        asm volatile("" ::: "memory");
#pragma unroll 1
        for (int c = 0; c < 32; ++c) {
            const float* prow = &pbuf[c & 1][0][lane];
            float* sp = gspk + (size_t)c * 16384;
            float* vp = gvmm + (size_t)c * 16384;
#pragma unroll
            for (int r = 0; r < 32; ++r) {
                const float pv = prow[r * 64];
                const bool sb = (pv >= 1.0f);
                float x = fminf(fmaf(4.0f, pv, -4.0f), 30.0f);
                const float ep = __expf(x);
                const float tt = 1.0f + ep;
                const float rr = __builtin_amdgcn_rcpf(tt * tt);
                const float s2 = sb ? 2.0f : 0.0f;
                const float so = fmaf(-4.0f * ep, rr, s2);
                const float vo = sb ? 0.0f : pv;
                acc += so;
                sp[r * 512] = so;
                vp[r * 512] = vo;
            }
            asm volatile("" ::: "memory");
            __builtin_amdgcn_s_barrier();             // barrier #(c+1)
            asm volatile("" ::: "memory");
        }
#pragma unroll
        for (int o = 32; o; o >>= 1) acc += __shfl_down(acc, o);
        if (lane == 0) partials[bid] = acc;
    }
}

// ===========================================================================
// Pass 3b: ALIAS-SAFE fallback scan (cur may be the vmem region).
// ===========================================================================
__device__ __forceinline__ void lif_step(float c, float& v, float& isyn,
                                         float& so_out)
{
    constexpr float A_M  = 0.95122942450071400910f;
    constexpr float OM_M = 1.0f - A_M;
    constexpr float A_S  = 0.81873075307798182354f;
    isyn = fmaf(A_S, isyn, c);
    v    = fmaf(A_M, v, OM_M * isyn);
    const float sp = (v >= 1.0f) ? 1.0f : 0.0f;
    float x = fmaf(4.0f, v, -4.0f);
    x = fminf(x, 30.0f);
    const float ep = __expf(x);
    const float tt = 1.0f + ep;
    const float surr = 4.0f * ep * __builtin_amdgcn_rcpf(tt * tt);
    so_out = fmaf(2.0f, sp, -surr);
    v = (sp > 0.f) ? 0.0f : v;
}

__global__ __launch_bounds__(64) void lif_scan(
    const float* cur, float* spikes, float* vmem, float* vfinal, float* partials)
{
    const int tid = threadIdx.x;
    const int gid = blockIdx.x * 64 + tid;
    const size_t base = ((size_t)(gid >> 9)) * (size_t)Tsz * Hsz + (gid & 511);

    float v = 0.f, isyn = 0.f, acc = 0.f;
    constexpr int P = 8;
    float ring[P];
#pragma unroll
    for (int p = 0; p < P; ++p) ring[p] = cur[base + (size_t)p * Hsz];

    for (int t = 0; t < Tsz; t += P) {
#pragma unroll
        for (int p = 0; p < P; ++p) {
            const float c = ring[p];
            int tn = t + P + p;
            tn = tn < (Tsz - 1) ? tn : (Tsz - 1);
            ring[p] = cur[base + (size_t)tn * Hsz];

            float so;
            lif_step(c, v, isyn, so);
            const size_t idx = base + (size_t)(t + p) * Hsz;
            spikes[idx] = so;
            vmem[idx]   = v;
            acc += so;
        }
    }
    vfinal[gid] = v;
#pragma unroll
    for (int off = 32; off; off >>= 1) acc += __shfl_down(acc, off);
    if (tid == 0) partials[blockIdx.x] = acc;
}

__global__ __launch_bounds__(256) void rate_finalize(
    const float* __restrict__ partials, float* __restrict__ rate)
{
    const int tid = threadIdx.x;
    float s = partials[tid];
#pragma unroll
    for (int off = 32; off; off >>= 1) s += __shfl_down(s, off);
    __shared__ float wsum[4];
    if ((tid & 63) == 0) wsum[tid >> 6] = s;
    __syncthreads();
    if (tid == 0)
        rate[0] = ((wsum[0] + wsum[1]) + (wsum[2] + wsum[3])) * (1.0f / 16777216.0f);
}

// ===========================================================================
extern "C" void kernel_launch(void* const* d_in, const int* in_sizes, int n_in,
                              void* d_out, int out_size, void* d_ws, size_t ws_size,
                              hipStream_t stream)
{
    const float* inputs = (const float*)d_in[0];
    const float* weight = (const float*)d_in[1];
    const float* bias   = (const float*)d_in[2];

    float* out    = (float*)d_out;
    float* spikes = out;
    float* vmem   = out + ELEMS;
    float* vfinal = out + 2 * ELEMS;
    float* rate   = vfinal + (size_t)Bsz * Hsz;

    float* partials = (float*)d_ws;                  // 256 floats
    char*  ws       = (char*)d_ws;

    const size_t HDR   = 16384;
    const size_t CUR_B = ELEMS * 4;                  // 64 MiB
    const size_t AH_B  = (size_t)Mtot * 1024 * 2;    // 64 MiB
    const size_t BH_B  = (size_t)Hsz * 1024 * 2;     // 1 MiB

    _Float16 *Ah, *Bh;
    float* cur;
    int path;
    if (ws_size >= HDR + CUR_B + AH_B + BH_B) {
        cur = (float*)(ws + HDR);
        Ah  = (_Float16*)(ws + HDR + CUR_B);
        Bh  = Ah + (size_t)Mtot * 1024;
        path = 0;
    } else if (ws_size >= HDR + CUR_B) {
        cur = (float*)(ws + HDR);
        Ah  = (_Float16*)d_out;                      // scan overwrites later
        Bh  = Ah + (size_t)Mtot * 1024;
        path = 1;
    } else {
        cur = vmem;
        Ah = Bh = nullptr;
        path = 2;
    }

    if (path != 2) {
        split_fp16x2<<<dim3(4096 + 256), 256, 0, stream>>>(inputs, weight, Ah, Bh);
        gemm_f16k3<<<dim3(512), 256, 0, stream>>>(Ah, Bh, bias, cur);
        lif_scan_pc<<<dim3(256), 128, 0, stream>>>(cur, spikes, vmem, vfinal, partials);
    } else {
        sgemm_currents<<<dim3(4, 256), 256, 0, stream>>>(inputs, weight, bias, cur);
        lif_scan<<<dim3(256), 64, 0, stream>>>(cur, spikes, vmem, vfinal, partials);
    }
    rate_finalize<<<dim3(1), 256, 0, stream>>>(partials, rate);
}

// Round 17
// 133.787 us; speedup vs baseline: 1.1732x; 1.0406x over previous
//
#include <hip/hip_runtime.h>

typedef unsigned short ushort_t;
typedef unsigned int   uint_t;
typedef float    float4v __attribute__((ext_vector_type(4)));
typedef _Float16 h16x8   __attribute__((ext_vector_type(8)));

#define Bsz 32
#define Tsz 1024
#define Din 512
#define Hsz 512
#define Mtot (Bsz * Tsz)                 // 32768
#define ELEMS ((size_t)Mtot * Hsz)       // 16777216

#define GLL16(gp, lp) __builtin_amdgcn_global_load_lds(                        \
    (const __attribute__((address_space(1))) unsigned int*)(gp),               \
    (__attribute__((address_space(3))) unsigned int*)(lp), 16, 0, 0)

#define GLL4(gp, lp) __builtin_amdgcn_global_load_lds(                         \
    (const __attribute__((address_space(1))) unsigned int*)(gp),               \
    (__attribute__((address_space(3))) unsigned int*)(lp), 4, 0, 0)

// ===========================================================================
// Pass 1: exact 2-limb fp16 truncation split with power-of-2 pre-scaling.
// ===========================================================================
__global__ __launch_bounds__(256) void split_fp16x2(
    const float* __restrict__ A, const float* __restrict__ W,
    _Float16* __restrict__ Ah, _Float16* __restrict__ Bh)
{
    const int bid = blockIdx.x, tid = threadIdx.x;
    if (bid < 4096) {
        const size_t e   = ((size_t)bid * 256 + tid) * 16;
        const int    row = (int)(e >> 9);
        const int    col = (int)(e & 511);
        const float4* Af = (const float4*)(A + e);
        h16x8 v0a, v1a, v0b, v1b;
#pragma unroll
        for (int q = 0; q < 4; ++q) {
            float4 x = Af[q];
            const float c[4] = {x.x, x.y, x.z, x.w};
#pragma unroll
            for (int j = 0; j < 4; ++j) {
                const float xs = c[j] * 256.0f;
                const _Float16 h0 = (_Float16)xs;
                const float rf = xs - (float)h0;
                const _Float16 h1 = (_Float16)rf;
                const int idx = q * 4 + j;
                if (idx < 8) { v0a[idx] = h0; v1a[idx] = h1; }
                else         { v0b[idx - 8] = h0; v1b[idx - 8] = h1; }
            }
        }
        _Float16* d0 = Ah + (size_t)row * 1024 + col;
        *(h16x8*)(d0)           = v0a;
        *(h16x8*)(d0 + 8)       = v0b;
        *(h16x8*)(d0 + 512)     = v1a;
        *(h16x8*)(d0 + 512 + 8) = v1b;
    } else {
        const int f4 = (bid - 4096) * 256 + tid;
        const int k  = f4 >> 7;
        const int n4 = (f4 & 127) << 2;
        float4 x = *(const float4*)(W + (size_t)k * Hsz + n4);
        const float c[4] = {x.x, x.y, x.z, x.w};
#pragma unroll
        for (int j = 0; j < 4; ++j) {
            const float ws = c[j] * 2048.0f;
            const _Float16 h0 = (_Float16)ws;
            const float rf = ws - (float)h0;
            const _Float16 h1 = (_Float16)rf;
            _Float16* d = Bh + (size_t)(n4 + j) * 1024 + k;
            d[0]   = h0;
            d[512] = h1;
        }
    }
}

// ===========================================================================
// Pass 2: fp16 2-limb 3-product MFMA GEMM (A0B0 + A0B1 + A1B0) * 2^-19.
// (byte-identical to R9-R16 — verified passing)
// ===========================================================================
#define SA_STAGE(LIMB, KK, SLOTBASE) do {                                      \
    const char* g_ = Ag + (size_t)((LIMB) * 1024) + (size_t)((KK) * 64);       \
    _Pragma("unroll") for (int H = 0; H < 4; ++H)                              \
        GLL16(g_ + (size_t)H * 131072, ldsA + (SLOTBASE) + H * 4096 + lsd);    \
} while (0)

#define SB_STAGE(LIMB, KK, SLOT) do {                                          \
    const char* g_ = Bg + (size_t)((LIMB) * 1024) + (size_t)((KK) * 64);       \
    _Pragma("unroll") for (int H = 0; H < 2; ++H)                              \
        GLL16(g_ + (size_t)H * 131072, ldsB + (SLOT) * 8192 + H * 4096 + lsd); \
} while (0)

#define LD_AF(SLOTBASE) do {                                                   \
    _Pragma("unroll") for (int mf = 0; mf < 8; ++mf)                           \
        af[mf] = *(const h16x8*)(ldsA + (SLOTBASE) + (wm + mf * 16 + lr) * 64  \
                                 + physf * 16);                                \
} while (0)

#define LD_BF(DST, SLOT) do {                                                  \
    _Pragma("unroll") for (int nf = 0; nf < 4; ++nf)                           \
        DST[nf] = *(const h16x8*)(ldsB + (SLOT) * 8192 + (wn + nf * 16 + lr)   \
                                  * 64 + physf * 16);                          \
} while (0)

#define MFMAH(BF) do { __builtin_amdgcn_s_setprio(1);                          \
    _Pragma("unroll") for (int mf = 0; mf < 8; ++mf)                           \
    _Pragma("unroll") for (int nf = 0; nf < 4; ++nf)                           \
        acc[mf][nf] = __builtin_amdgcn_mfma_f32_16x16x32_f16(                  \
            af[mf], BF[nf], acc[mf][nf], 0, 0, 0);                             \
    __builtin_amdgcn_s_setprio(0); } while (0)

#define GATE(N) do { asm volatile("s_waitcnt vmcnt(" #N ")" ::: "memory");     \
    __builtin_amdgcn_sched_barrier(0); __builtin_amdgcn_s_barrier();           \
    asm volatile("" ::: "memory"); } while (0)

__global__ __launch_bounds__(256, 2) void gemm_f16k3(
    const _Float16* __restrict__ Ah, const _Float16* __restrict__ Bh,
    const float* __restrict__ bias, float* __restrict__ C)
{
    __shared__ __align__(16) char lds[65536];
    char* ldsA = lds;
    char* ldsB = lds + 32768;

    const int tid = threadIdx.x;
    const int bid = blockIdx.x;
    const int lin = ((bid & 7) << 6) | (bid >> 3);
    const int m0  = (lin >> 2) << 8;
    const int n0  = (lin & 3) << 7;
    const int w = tid >> 6, lane = tid & 63;
    const int wm = (w & 1) << 7;
    const int wn = (w >> 1) << 6;
    const int lr = lane & 15, lg = lane >> 4;

    const int physf = lg ^ (lr & 3) ^ ((lr >> 2) & 3);

    const int srow = tid >> 2;
    const int schk = tid & 3;
    const int logchk = schk ^ (srow & 3) ^ ((srow >> 2) & 3);
    const int lsd = tid * 16;
    const char* Ag = (const char*)Ah + (size_t)(m0 + srow) * 2048 + logchk * 16;
    const char* Bg = (const char*)Bh + (size_t)(n0 + srow) * 2048 + logchk * 16;

    float4v acc[8][4];
#pragma unroll
    for (int i = 0; i < 8; ++i)
#pragma unroll
        for (int j = 0; j < 4; ++j) acc[i][j] = (float4v)0.f;

    h16x8 af[8], bf0[4], bf1[4];

    SA_STAGE(0, 0, 0);
    SB_STAGE(0, 0, 0); SB_STAGE(1, 0, 1);
    SB_STAGE(0, 1, 2); SB_STAGE(1, 1, 3);
    GATE(0);

#pragma unroll 1
    for (int k = 0; k < 15; ++k) {
        const int s0 = (2 * k) & 3, s1 = (2 * k + 1) & 3;
        GATE(4);
        LD_AF(0); LD_BF(bf0, s0);
        SA_STAGE(1, k, 16384);
        MFMAH(bf0);
        GATE(4);
        LD_BF(bf1, s1);
        SA_STAGE(0, k + 1, 0);
        MFMAH(bf1);
        GATE(4);
        LD_AF(16384);
        if (k < 14) { SB_STAGE(0, k + 2, s0); SB_STAGE(1, k + 2, s1); }
        MFMAH(bf0);
    }
    {
        GATE(0);
        LD_AF(0); LD_BF(bf0, 2);
        SA_STAGE(1, 15, 16384);
        MFMAH(bf0);
        GATE(4);
        LD_BF(bf1, 3);
        MFMAH(bf1);
        GATE(0);
        LD_AF(16384);
        MFMAH(bf0);
    }

    constexpr float INVS = 1.0f / 524288.0f;
#pragma unroll
    for (int nf = 0; nf < 4; ++nf) {
        const int col = n0 + wn + nf * 16 + lr;
        const float bv = bias[col];
#pragma unroll
        for (int mf = 0; mf < 8; ++mf)
#pragma unroll
            for (int j = 0; j < 4; ++j) {
                const int row = m0 + wm + mf * 16 + lg * 4 + j;
                C[(size_t)row * Hsz + col] = fmaf(acc[mf][nf][j], INVS, bv);
            }
    }
}

// ===========================================================================
// Fallback fp32 GEMM (only if d_ws too small)
// ===========================================================================
#define BM 128
#define BN 128
#define BK 16
#define LDSA (BM + 4)
#define LDSB (BN + 4)
__global__ __launch_bounds__(256) void sgemm_currents(
    const float* __restrict__ A, const float* __restrict__ B,
    const float* __restrict__ bias, float* __restrict__ C)
{
    __shared__ float As[BK][LDSA];
    __shared__ float Bs[BK][LDSB];
    const int tid = threadIdx.x;
    const int tx = tid & 15, ty = tid >> 4;
    const int m0 = blockIdx.y * BM, n0 = blockIdx.x * BN;
    const int arow = tid >> 2, ac4 = (tid & 3) * 4;
    const int brow = tid >> 5, bc4 = (tid & 31) * 4;
    float acc[8][8];
#pragma unroll
    for (int i = 0; i < 8; ++i)
#pragma unroll
        for (int j = 0; j < 8; ++j) acc[i][j] = 0.f;
    const float* Abase = A + (size_t)(m0 + arow) * Din + ac4;
    const float* Bbase = B + (size_t)brow * Hsz + n0 + bc4;
    float4 a0 = *(const float4*)Abase;
    float4 a1 = *(const float4*)(Abase + (size_t)64 * Din);
    float4 b0 = *(const float4*)Bbase;
    float4 b1 = *(const float4*)(Bbase + (size_t)8 * Hsz);
    const int NKT = Din / BK;
    for (int kt = 0; kt < NKT; ++kt) {
        const float* apf = (const float*)&a0;
        const float* aqf = (const float*)&a1;
#pragma unroll
        for (int j = 0; j < 4; ++j) As[ac4 + j][arow] = apf[j];
#pragma unroll
        for (int j = 0; j < 4; ++j) As[ac4 + j][arow + 64] = aqf[j];
        *(float4*)&Bs[brow][bc4] = b0;
        *(float4*)&Bs[brow + 8][bc4] = b1;
        __syncthreads();
        if (kt + 1 < NKT) {
            const float* An = Abase + (kt + 1) * BK;
            const float* Bn = Bbase + (size_t)(kt + 1) * BK * Hsz;
            a0 = *(const float4*)An;
            a1 = *(const float4*)(An + (size_t)64 * Din);
            b0 = *(const float4*)Bn;
            b1 = *(const float4*)(Bn + (size_t)8 * Hsz);
        }
#pragma unroll
        for (int k = 0; k < BK; ++k) {
            float4 af0 = *(const float4*)&As[k][ty * 8];
            float4 af1 = *(const float4*)&As[k][ty * 8 + 4];
            float4 bf0 = *(const float4*)&Bs[k][tx * 8];
            float4 bf1 = *(const float4*)&Bs[k][tx * 8 + 4];
            const float av[8] = {af0.x, af0.y, af0.z, af0.w, af1.x, af1.y, af1.z, af1.w};
            const float bv[8] = {bf0.x, bf0.y, bf0.z, bf0.w, bf1.x, bf1.y, bf1.z, bf1.w};
#pragma unroll
            for (int i = 0; i < 8; ++i)
#pragma unroll
                for (int j = 0; j < 8; ++j) acc[i][j] = fmaf(av[i], bv[j], acc[i][j]);
        }
        __syncthreads();
    }
    const float4 bi0 = *(const float4*)&bias[n0 + tx * 8];
    const float4 bi1 = *(const float4*)&bias[n0 + tx * 8 + 4];
#pragma unroll
    for (int i = 0; i < 8; ++i) {
        const size_t row = (size_t)(m0 + ty * 8 + i);
        float4 o0 = make_float4(acc[i][0] + bi0.x, acc[i][1] + bi0.y,
                                acc[i][2] + bi0.z, acc[i][3] + bi0.w);
        float4 o1 = make_float4(acc[i][4] + bi1.x, acc[i][5] + bi1.y,
                                acc[i][6] + bi1.z, acc[i][7] + bi1.w);
        float* cp = C + row * Hsz + n0 + tx * 8;
        *(float4*)cp = o0;
        *(float4*)(cp + 4) = o1;
    }
}

// ===========================================================================
// Pass 3a: producer + 3-consumer LIF scan (non-aliased). 256 blocks x 256
// thr = 4 waves, one per SIMD (producer's serial chain gets a SIMD alone).
//   Wave 0 (producer): GLL4-prefetch cur, recursion, v_pre -> pbuf ring.
//   Waves 1-3 (consumers): rows 0-10 / 11-21 / 22-31 of each chunk:
//     surrogate + both global stores. Per-consumer issue ~= 1/3 of R16's
//     single consumer -> store-BW / producer becomes the limiter.
// Sync: identical 33-barrier ledger per wave (R16-verified); pbuf parity
// write(k)/read(k+1)/overwrite(k+2) barrier-separated; lbuf producer-only.
// Consumer stores never drained in-loop (compiler-tracked).
// ===========================================================================
__global__ __launch_bounds__(256) void lif_scan_pc(
    const float* __restrict__ cur, float* __restrict__ spikes,
    float* __restrict__ vmem, float* __restrict__ vfinal,
    float* __restrict__ partials)
{
    __shared__ __align__(16) float lbuf[2][32][64];   // cur ring (producer)
    __shared__ __align__(16) float pbuf[2][32][64];   // v_pre ring (P->C)

    constexpr float A_M  = 0.95122942450071400910f;
    constexpr float OM_M = 1.0f - A_M;
    constexpr float A_S  = 0.81873075307798182354f;

    const int tid  = threadIdx.x;
    const int lane = tid & 63;
    const int wv   = tid >> 6;                        // 0=prod, 1..3=cons
    const int bid  = blockIdx.x;
    const int batch = bid >> 3;
    const int hbase = (bid & 7) << 6;
    const size_t sbase = (size_t)batch * (size_t)(Tsz * Hsz) + hbase + lane;

    if (wv == 0) {
        // ---------------- producer: recursion ----------------
        const float* gsrc = cur + sbase;
#pragma unroll
        for (int r = 0; r < 32; ++r)
            GLL4(gsrc + r * 512, &lbuf[0][r][0]);
        asm volatile("s_waitcnt vmcnt(0)" ::: "memory");
        __builtin_amdgcn_sched_barrier(0);

        float v = 0.f, isyn = 0.f;
#pragma unroll 1
        for (int c = 0; c < 32; ++c) {
            if (c < 31) {
                const float* gs = gsrc + (size_t)(c + 1) * 16384;
                float (*db)[64] = lbuf[(c + 1) & 1];
#pragma unroll
                for (int r = 0; r < 32; ++r)
                    GLL4(gs + r * 512, &db[r][0]);
            }
            const float* lrow = &lbuf[c & 1][0][lane];
            float* prow = &pbuf[c & 1][0][lane];
#pragma unroll
            for (int r = 0; r < 32; ++r) {
                isyn = fmaf(A_S, isyn, lrow[r * 64]);
                v    = fmaf(A_M, v, OM_M * isyn);
                prow[r * 64] = v;                     // v_pre
                v = (v >= 1.0f) ? 0.0f : v;           // reset carry
            }
            asm volatile("s_waitcnt vmcnt(0) lgkmcnt(0)" ::: "memory");
            __builtin_amdgcn_sched_barrier(0);
            __builtin_amdgcn_s_barrier();             // barrier #c
            asm volatile("" ::: "memory");
        }
        vfinal[bid * 64 + lane] = v;
        __builtin_amdgcn_s_barrier();                 // barrier #32
    } else {
        // ------------- consumers: surrogate + stores -------------
        const int cj = wv - 1;                        // 0..2
        const int r0 = cj * 11;                       // 0,11,22
        const int rn = (cj == 2) ? 10 : 11;           // 11,11,10 rows
        float* gspk = spikes + sbase;
        float* gvmm = vmem + sbase;
        float acc = 0.f;

        __builtin_amdgcn_s_barrier();                 // barrier #0
        asm volatile("" ::: "memory");
#pragma unroll 1
        for (int c = 0; c < 32; ++c) {
            const float* prow = &pbuf[c & 1][0][lane];
            float* sp = gspk + (size_t)c * 16384;
            float* vp = gvmm + (size_t)c * 16384;
#pragma unroll
            for (int k = 0; k < 11; ++k) {
                if (k < rn) {                         // wave-uniform bound
                    const int r = r0 + k;
                    const float pv = prow[r * 64];
                    const bool sb = (pv >= 1.0f);
                    float x = fminf(fmaf(4.0f, pv, -4.0f), 30.0f);
                    const float ep = __expf(x);
                    const float tt = 1.0f + ep;
                    const float rr = __builtin_amdgcn_rcpf(tt * tt);
                    const float s2 = sb ? 2.0f : 0.0f;
                    const float so = fmaf(-4.0f * ep, rr, s2);
                    const float vo = sb ? 0.0f : pv;
                    acc += so;
                    sp[r * 512] = so;
                    vp[r * 512] = vo;
                }
            }
            asm volatile("" ::: "memory");
            __builtin_amdgcn_s_barrier();             // barrier #(c+1)
            asm volatile("" ::: "memory");
        }
#pragma unroll
        for (int o = 32; o; o >>= 1) acc += __shfl_down(acc, o);
        if (lane == 0) partials[cj * 256 + bid] = acc;
    }
}

// ===========================================================================
// Pass 3b: ALIAS-SAFE fallback scan (cur may be the vmem region).
// ===========================================================================
__device__ __forceinline__ void lif_step(float c, float& v, float& isyn,
                                         float& so_out)
{
    constexpr float A_M  = 0.95122942450071400910f;
    constexpr float OM_M = 1.0f - A_M;
    constexpr float A_S  = 0.81873075307798182354f;
    isyn = fmaf(A_S, isyn, c);
    v    = fmaf(A_M, v, OM_M * isyn);
    const float sp = (v >= 1.0f) ? 1.0f : 0.0f;
    float x = fmaf(4.0f, v, -4.0f);
    x = fminf(x, 30.0f);
    const float ep = __expf(x);
    const float tt = 1.0f + ep;
    const float surr = 4.0f * ep * __builtin_amdgcn_rcpf(tt * tt);
    so_out = fmaf(2.0f, sp, -surr);
    v = (sp > 0.f) ? 0.0f : v;
}

__global__ __launch_bounds__(64) void lif_scan(
    const float* cur, float* spikes, float* vmem, float* vfinal, float* partials)
{
    const int tid = threadIdx.x;
    const int gid = blockIdx.x * 64 + tid;
    const size_t base = ((size_t)(gid >> 9)) * (size_t)Tsz * Hsz + (gid & 511);

    float v = 0.f, isyn = 0.f, acc = 0.f;
    constexpr int P = 8;
    float ring[P];
#pragma unroll
    for (int p = 0; p < P; ++p) ring[p] = cur[base + (size_t)p * Hsz];

    for (int t = 0; t < Tsz; t += P) {
#pragma unroll
        for (int p = 0; p < P; ++p) {
            const float c = ring[p];
            int tn = t + P + p;
            tn = tn < (Tsz - 1) ? tn : (Tsz - 1);
            ring[p] = cur[base + (size_t)tn * Hsz];

            float so;
            lif_step(c, v, isyn, so);
            const size_t idx = base + (size_t)(t + p) * Hsz;
            spikes[idx] = so;
            vmem[idx]   = v;
            acc += so;
        }
    }
    vfinal[gid] = v;
#pragma unroll
    for (int off = 32; off; off >>= 1) acc += __shfl_down(acc, off);
    if (tid == 0) partials[blockIdx.x] = acc;
}

__global__ __launch_bounds__(256) void rate_finalize(
    const float* __restrict__ partials, float* __restrict__ rate)
{
    const int tid = threadIdx.x;
    float s = partials[tid];
#pragma unroll
    for (int off = 32; off; off >>= 1) s += __shfl_down(s, off);
    __shared__ float wsum[4];
    if ((tid & 63) == 0) wsum[tid >> 6] = s;
    __syncthreads();
    if (tid == 0)
        rate[0] = ((wsum[0] + wsum[1]) + (wsum[2] + wsum[3])) * (1.0f / 16777216.0f);
}

__global__ __launch_bounds__(256) void rate_finalize3(
    const float* __restrict__ partials, float* __restrict__ rate)
{
    const int tid = threadIdx.x;
    float s = partials[tid] + partials[256 + tid] + partials[512 + tid];
#pragma unroll
    for (int off = 32; off; off >>= 1) s += __shfl_down(s, off);
    __shared__ float wsum[4];
    if ((tid & 63) == 0) wsum[tid >> 6] = s;
    __syncthreads();
    if (tid == 0)
        rate[0] = ((wsum[0] + wsum[1]) + (wsum[2] + wsum[3])) * (1.0f / 16777216.0f);
}

// ===========================================================================
extern "C" void kernel_launch(void* const* d_in, const int* in_sizes, int n_in,
                              void* d_out, int out_size, void* d_ws, size_t ws_size,
                              hipStream_t stream)
{
    const float* inputs = (const float*)d_in[0];
    const float* weight = (const float*)d_in[1];
    const float* bias   = (const float*)d_in[2];

    float* out    = (float*)d_out;
    float* spikes = out;
    float* vmem   = out + ELEMS;
    float* vfinal = out + 2 * ELEMS;
    float* rate   = vfinal + (size_t)Bsz * Hsz;

    float* partials = (float*)d_ws;                  // 3*256 floats
    char*  ws       = (char*)d_ws;

    const size_t HDR   = 16384;
    const size_t CUR_B = ELEMS * 4;                  // 64 MiB
    const size_t AH_B  = (size_t)Mtot * 1024 * 2;    // 64 MiB
    const size_t BH_B  = (size_t)Hsz * 1024 * 2;     // 1 MiB

    _Float16 *Ah, *Bh;
    float* cur;
    int path;
    if (ws_size >= HDR + CUR_B + AH_B + BH_B) {
        cur = (float*)(ws + HDR);
        Ah  = (_Float16*)(ws + HDR + CUR_B);
        Bh  = Ah + (size_t)Mtot * 1024;
        path = 0;
    } else if (ws_size >= HDR + CUR_B) {
        cur = (float*)(ws + HDR);
        Ah  = (_Float16*)d_out;                      // scan overwrites later
        Bh  = Ah + (size_t)Mtot * 1024;
        path = 1;
    } else {
        cur = vmem;
        Ah = Bh = nullptr;
        path = 2;
    }

    if (path != 2) {
        split_fp16x2<<<dim3(4096 + 256), 256, 0, stream>>>(inputs, weight, Ah, Bh);
        gemm_f16k3<<<dim3(512), 256, 0, stream>>>(Ah, Bh, bias, cur);
        lif_scan_pc<<<dim3(256), 256, 0, stream>>>(cur, spikes, vmem, vfinal, partials);
        rate_finalize3<<<dim3(1), 256, 0, stream>>>(partials, rate);
    } else {
        sgemm_currents<<<dim3(4, 256), 256, 0, stream>>>(inputs, weight, bias, cur);
        lif_scan<<<dim3(256), 64, 0, stream>>>(cur, spikes, vmem, vfinal, partials);
        rate_finalize<<<dim3(1), 256, 0, stream>>>(partials, rate);
    }
}